// Round 9
// baseline (640.389 us; speedup 1.0000x reference)
//
#include <hip/hip_runtime.h>

#define D_IN  128
#define D_H   64
#define D_OUT 40

// ---- bf16 helpers (bit ops; RTNE pack) ----
__device__ __forceinline__ float bf_lo(unsigned u){ return __uint_as_float(u << 16); }
__device__ __forceinline__ float bf_hi(unsigned u){ return __uint_as_float(u & 0xFFFF0000u); }
__device__ __forceinline__ unsigned bf_pack(float a, float b){
  unsigned ua = __float_as_uint(a), ub = __float_as_uint(b);
  unsigned lo = (ua + 0x7FFFu + ((ua >> 16) & 1u)) >> 16;
  unsigned hi = (ub + 0x7FFFu + ((ub >> 16) & 1u)) & 0xFFFF0000u;
  return hi | lo;
}

// ---------------- CSR build: deg+pos in one atomic pass, then pure scatter ------

__launch_bounds__(256)
static __global__ void k_degpos(const int* __restrict__ dst, int* __restrict__ deg,
                                int* __restrict__ pos, int E){
  int base = (blockIdx.x*256 + threadIdx.x) * 4;
  if (base + 4 <= E){
    int4 d = *(const int4*)(dst + base);
    int4 p;
    p.x = atomicAdd(&deg[d.x], 1);
    p.y = atomicAdd(&deg[d.y], 1);
    p.z = atomicAdd(&deg[d.z], 1);
    p.w = atomicAdd(&deg[d.w], 1);
    *(int4*)(pos + base) = p;
  } else {
    for (int i = base; i < E; i++) pos[i] = atomicAdd(&deg[dst[i]], 1);
  }
}

static __global__ void k_scan1(const int* __restrict__ deg, int* __restrict__ incl,
                               int* __restrict__ bsums, int n){
  __shared__ int s[1024];
  int t = threadIdx.x; int g = blockIdx.x*1024 + t;
  int v = (g < n) ? deg[g] : 0;
  s[t] = v; __syncthreads();
  for (int off = 1; off < 1024; off <<= 1){
    int u = (t >= off) ? s[t-off] : 0; __syncthreads();
    s[t] += u; __syncthreads();
  }
  if (g < n) incl[g] = s[t];
  if (t == 1023) bsums[blockIdx.x] = s[1023];
}

static __global__ void k_scan2(int* bsums, int nb){
  __shared__ int s[128];
  int t = threadIdx.x;
  int v = (t < nb) ? bsums[t] : 0;
  s[t] = v; __syncthreads();
  for (int off = 1; off < 128; off <<= 1){
    int u = (t >= off) ? s[t-off] : 0; __syncthreads();
    s[t] += u; __syncthreads();
  }
  if (t < nb) bsums[t] = s[t] - v;   // exclusive block offsets
}

static __global__ void k_scan3(const int* __restrict__ deg, int* __restrict__ rs,
                               const int* __restrict__ bsums,
                               float* __restrict__ dinv, int n){
  int t = threadIdx.x; int g = blockIdx.x*1024 + t;
  if (g < n){
    int excl = rs[g] - deg[g] + bsums[blockIdx.x];
    rs[g] = excl;
    dinv[g] = rsqrtf((float)(deg[g] + 1));   // +1 = self loop
  }
}

__launch_bounds__(256)
static __global__ void k_scatter(const int* __restrict__ src, const int* __restrict__ dst,
                                 const int* __restrict__ pos, const int* __restrict__ rs,
                                 int* __restrict__ col, int E){
  int base = (blockIdx.x*256 + threadIdx.x) * 4;
  if (base + 4 <= E){
    int4 d = *(const int4*)(dst + base);
    int4 s = *(const int4*)(src + base);
    int4 p = *(const int4*)(pos + base);
    col[rs[d.x] + p.x] = s.x;
    col[rs[d.y] + p.y] = s.y;
    col[rs[d.z] + p.z] = s.z;
    col[rs[d.w] + p.w] = s.w;
  } else {
    for (int i = base; i < E; i++) col[rs[dst[i]] + pos[i]] = src[i];
  }
}

// ---------------- fold delete-MLP into GEMM2: M = Wd1^T @ Wc2, bvec = bd1 @ Wc2 -----

static __global__ void k_pre(const float* __restrict__ Wd1, const float* __restrict__ bd1,
                             const float* __restrict__ Wc2, float* __restrict__ M,
                             float* __restrict__ bvec){
  int t = threadIdx.x;
  for (int i = t; i < D_H*D_OUT; i += 256){
    int q = i / D_OUT, j = i % D_OUT;
    float s = 0.f;
    for (int k = 0; k < D_H; k++) s += Wd1[k*D_H + q] * Wc2[k*D_OUT + j];
    M[i] = s;
  }
  if (t < D_OUT){
    float s = 0.f;
    for (int k = 0; k < D_H; k++) s += bd1[k] * Wc2[k*D_OUT + t];
    bvec[t] = s;
  }
}

// ---------------- GEMM1: quarter-sharded bf16 output ----------------
// hq1[q][node][16 bf16], q = feature/16; quarter array = N*32B (3.2 MB, L2-fits).

__launch_bounds__(256)
static __global__ void k_gemm1(const float* __restrict__ x, const float* __restrict__ Wc1,
                               const float* __restrict__ dinv,
                               unsigned short* __restrict__ hq1, int n, int Q1){
  __shared__ float Wl[D_IN*D_H];        // 32 KB
  __shared__ float xs[32][D_IN+1];      // padded
  int t = threadIdx.x;
  int base = blockIdx.x*32;
  for (int i = t; i < D_IN*D_H; i += 256) Wl[i] = Wc1[i];
  for (int i = t; i < 32*D_IN; i += 256){
    int r = i >> 7, c = i & 127;
    int node = base + r;
    xs[r][c] = (node < n) ? x[(size_t)node*D_IN + c] : 0.f;
  }
  __syncthreads();
  int nl = t >> 3, j0 = (t & 7)*8;
  int node = base + nl;
  if (node >= n) return;
  float acc[8] = {0,0,0,0,0,0,0,0};
  #pragma unroll 4
  for (int k = 0; k < D_IN; k++){
    float xv = xs[nl][k];
    #pragma unroll
    for (int jj = 0; jj < 8; jj++) acc[jj] += xv * Wl[k*D_H + j0 + jj];
  }
  float dv = dinv[node];
  uint4 o;
  o.x = bf_pack(acc[0]*dv, acc[1]*dv);
  o.y = bf_pack(acc[2]*dv, acc[3]*dv);
  o.z = bf_pack(acc[4]*dv, acc[5]*dv);
  o.w = bf_pack(acc[6]*dv, acc[7]*dv);
  int q = j0 >> 4;
  *(uint4*)(hq1 + (size_t)q*Q1 + (size_t)node*16 + (j0 & 15)) = o;
}

// ---------------- agg1 (quarter q per block): h = relu(dinv*(self+sum)+bc1) -----
// blockIdx%8 -> XCD (round-robin); q=(b%8)>>1 pins each quarter to 2 XCDs so the
// 3.2MB quarter array stays L2-resident. 16 edges in flight (16 grp x 4 lanes).

__launch_bounds__(256)
static __global__ void k_agg1(const unsigned short* __restrict__ hq1, const int* __restrict__ rs,
                              const int* __restrict__ deg, const int* __restrict__ col,
                              const float* __restrict__ dinv, const float* __restrict__ bc1,
                              float* __restrict__ h, int n, int Q1){
  int b = blockIdx.x;
  int q = (b & 7) >> 1;
  int j = ((b >> 3) << 1) | (b & 1);
  int t = threadIdx.x;
  int wave = t >> 6, lane = t & 63;
  int node = j*4 + wave;
  if (node >= n) return;
  int grp = lane >> 2, fl = lane & 3;
  const uint2* g2 = (const uint2*)(hq1 + (size_t)q*Q1);   // row = 4 uint2 (32B)
  float a0=0.f, a1=0.f, a2=0.f, a3=0.f;
  if (grp == 0){
    uint2 v = g2[(size_t)node*4 + fl];                    // self loop
    a0 += bf_lo(v.x); a1 += bf_hi(v.x); a2 += bf_lo(v.y); a3 += bf_hi(v.y);
  }
  int s0 = rs[node], cnt = deg[node];
  #pragma unroll 2
  for (int e0 = 0; e0 < cnt; e0 += 16){
    int sl = e0 + grp;
    if (sl < cnt){
      int s = col[s0 + sl];                               // uniform within group
      uint2 v = g2[(size_t)s*4 + fl];
      a0 += bf_lo(v.x); a1 += bf_hi(v.x); a2 += bf_lo(v.y); a3 += bf_hi(v.y);
    }
  }
  a0 += __shfl_xor(a0,  4, 64); a1 += __shfl_xor(a1,  4, 64);
  a2 += __shfl_xor(a2,  4, 64); a3 += __shfl_xor(a3,  4, 64);
  a0 += __shfl_xor(a0,  8, 64); a1 += __shfl_xor(a1,  8, 64);
  a2 += __shfl_xor(a2,  8, 64); a3 += __shfl_xor(a3,  8, 64);
  a0 += __shfl_xor(a0, 16, 64); a1 += __shfl_xor(a1, 16, 64);
  a2 += __shfl_xor(a2, 16, 64); a3 += __shfl_xor(a3, 16, 64);
  a0 += __shfl_xor(a0, 32, 64); a1 += __shfl_xor(a1, 32, 64);
  a2 += __shfl_xor(a2, 32, 64); a3 += __shfl_xor(a3, 32, 64);
  if (grp == 0){
    float dv = dinv[node];
    float4 bb = *(const float4*)(bc1 + q*16 + fl*4);
    float4 o;
    o.x = fmaxf(a0*dv + bb.x, 0.f);
    o.y = fmaxf(a1*dv + bb.y, 0.f);
    o.z = fmaxf(a2*dv + bb.z, 0.f);
    o.w = fmaxf(a3*dv + bb.w, 0.f);
    *(float4*)(h + (size_t)node*D_H + q*16 + fl*4) = o;
  }
}

// ---------------- GEMM2: quarter-sharded padded-48 bf16 output -----------------
// hq2[q][node][12 bf16] (24B rows, 2.4MB/quarter); features q*12+m, zero-padded >=40.

__launch_bounds__(128)
static __global__ void k_gemm2(const float* __restrict__ h, const unsigned char* __restrict__ mask,
                               const float* __restrict__ Mmat, const float* __restrict__ bvec,
                               const float* __restrict__ Wc2, const float* __restrict__ dinv,
                               unsigned short* __restrict__ hq2, int n, int Q2){
  __shared__ float Ms[D_H*D_OUT];          // 10 KB
  __shared__ float Ws[D_H*D_OUT];          // 10 KB
  __shared__ float bv[D_OUT];
  __shared__ float hs[128*(D_H+1)];        // 33.3 KB, padded stride 65
  int t = threadIdx.x;
  int base = blockIdx.x*128;
  for (int i = t; i < D_H*D_OUT; i += 128){ Ms[i] = Mmat[i]; Ws[i] = Wc2[i]; }
  if (t < D_OUT) bv[t] = bvec[t];
  for (int i = t; i < 128*D_H; i += 128){
    int r = i >> 6, c = i & 63;
    int node = base + r;
    hs[r*(D_H+1) + c] = (node < n) ? h[(size_t)node*D_H + c] : 0.f;
  }
  __syncthreads();
  int node = base + t;
  if (node >= n) return;
  bool m = mask[node] != 0;
  const float* Wp = m ? Ms : Ws;
  float acc[D_OUT];
  #pragma unroll
  for (int j = 0; j < D_OUT; j++) acc[j] = m ? bv[j] : 0.f;
  const float* hrow = &hs[t*(D_H+1)];
  for (int qq = 0; qq < D_H; qq++){
    float hv = hrow[qq];
    #pragma unroll
    for (int j = 0; j < D_OUT; j++) acc[j] += hv * Wp[qq*D_OUT + j];
  }
  float dv = dinv[node];
  #pragma unroll
  for (int q = 0; q < 4; q++){
    unsigned short* op = hq2 + (size_t)q*Q2 + (size_t)node*12;
    #pragma unroll
    for (int k = 0; k < 3; k++){
      int j = q*12 + k*4;
      float f0 = (j+0 < D_OUT) ? acc[j+0]*dv : 0.f;
      float f1 = (j+1 < D_OUT) ? acc[j+1]*dv : 0.f;
      float f2 = (j+2 < D_OUT) ? acc[j+2]*dv : 0.f;
      float f3 = (j+3 < D_OUT) ? acc[j+3]*dv : 0.f;
      uint2 o; o.x = bf_pack(f0, f1); o.y = bf_pack(f2, f3);
      *(uint2*)(op + k*4) = o;
    }
  }
}

// ---------------- agg2 (quarter q per block) -> tmp (f32 40/node) ----------------
// Same 16-edges-in-flight structure; 3 of 4 lanes per group carry uint2. No LDS.

__launch_bounds__(256)
static __global__ void k_agg2(const unsigned short* __restrict__ hq2, const int* __restrict__ rs,
                              const int* __restrict__ deg, const int* __restrict__ col,
                              const float* __restrict__ dinv, const float* __restrict__ bc2,
                              float* __restrict__ tmp, int n, int Q2){
  int b = blockIdx.x;
  int q = (b & 7) >> 1;
  int j = ((b >> 3) << 1) | (b & 1);
  int t = threadIdx.x;
  int wave = t >> 6, lane = t & 63;
  int node = j*4 + wave;
  if (node >= n) return;
  int grp = lane >> 2, fl = lane & 3;
  bool fa = fl < 3;                                        // 3 uint2 = 12 bf16
  const uint2* g2 = (const uint2*)(hq2 + (size_t)q*Q2);    // row = 3 uint2 (24B)
  float a0=0.f, a1=0.f, a2=0.f, a3=0.f;
  if (grp == 0 && fa){
    uint2 v = g2[(size_t)node*3 + fl];                     // self loop
    a0 += bf_lo(v.x); a1 += bf_hi(v.x); a2 += bf_lo(v.y); a3 += bf_hi(v.y);
  }
  int s0 = rs[node], cnt = deg[node];
  #pragma unroll 2
  for (int e0 = 0; e0 < cnt; e0 += 16){
    int sl = e0 + grp;
    if (sl < cnt && fa){
      int s = col[s0 + sl];                                // uniform within group
      uint2 v = g2[(size_t)s*3 + fl];
      a0 += bf_lo(v.x); a1 += bf_hi(v.x); a2 += bf_lo(v.y); a3 += bf_hi(v.y);
    }
  }
  a0 += __shfl_xor(a0,  4, 64); a1 += __shfl_xor(a1,  4, 64);
  a2 += __shfl_xor(a2,  4, 64); a3 += __shfl_xor(a3,  4, 64);
  a0 += __shfl_xor(a0,  8, 64); a1 += __shfl_xor(a1,  8, 64);
  a2 += __shfl_xor(a2,  8, 64); a3 += __shfl_xor(a3,  8, 64);
  a0 += __shfl_xor(a0, 16, 64); a1 += __shfl_xor(a1, 16, 64);
  a2 += __shfl_xor(a2, 16, 64); a3 += __shfl_xor(a3, 16, 64);
  a0 += __shfl_xor(a0, 32, 64); a1 += __shfl_xor(a1, 32, 64);
  a2 += __shfl_xor(a2, 32, 64); a3 += __shfl_xor(a3, 32, 64);
  int j0 = q*12 + fl*4;
  if (grp == 0 && fa && j0 < D_OUT){
    float dv = dinv[node];
    float4 bb = *(const float4*)(bc2 + j0);
    float4 o;
    o.x = a0*dv + bb.x;
    o.y = a1*dv + bb.y;
    o.z = a2*dv + bb.z;
    o.w = a3*dv + bb.w;
    *(float4*)(tmp + (size_t)node*D_OUT + j0) = o;
  }
}

// ---------------- post: optional Wd2 delete epilogue, tmp -> out ----------------

__launch_bounds__(256)
static __global__ void k_post(const float* __restrict__ tmp, const unsigned char* __restrict__ mask,
                              const float* __restrict__ Wd2, const float* __restrict__ bd2,
                              float* __restrict__ out, int n){
  __shared__ float4 wds4[D_OUT*11];        // Wd2 row j at wds4[j*11+q]
  __shared__ float  bds[D_OUT];
  __shared__ float4 os4[4][11];
  int t = threadIdx.x;
  for (int i = t; i < D_OUT*10; i += 256){
    int jj = i / 10, qq = i % 10;
    const float* wr = Wd2 + jj*D_OUT + qq*4;
    wds4[jj*11 + qq] = make_float4(wr[0], wr[1], wr[2], wr[3]);
  }
  if (t < D_OUT) bds[t] = bd2[t];
  __syncthreads();
  int wave = t >> 6, lane = t & 63;
  int node = blockIdx.x*4 + wave;
  if (node >= n) return;
  const float4* trow = (const float4*)(tmp + (size_t)node*D_OUT);
  if (mask[node] != 0){                    // wave-uniform branch
    if (lane < 10) os4[wave][lane] = trow[lane];   // stage res row
    float r = (lane < D_OUT) ? bds[lane] : 0.f;
    #pragma unroll
    for (int qq = 0; qq < 10; qq++){
      float4 hv = os4[wave][qq];                   // broadcast read
      if (lane < D_OUT){
        float4 wv = wds4[lane*11 + qq];
        r += hv.x*wv.x + hv.y*wv.y + hv.z*wv.z + hv.w*wv.w;
      }
    }
    if (lane < D_OUT) out[(size_t)node*D_OUT + lane] = r;
  } else {
    if (lane < 10) ((float4*)(out + (size_t)node*D_OUT))[lane] = trow[lane];
  }
}

// ---------------- launcher ----------------

extern "C" void kernel_launch(void* const* d_in, const int* in_sizes, int n_in,
                              void* d_out, int out_size, void* d_ws, size_t ws_size,
                              hipStream_t stream){
  const float* x    = (const float*)d_in[0];
  const int*   ei   = (const int*)d_in[1];
  const unsigned char* mask = (const unsigned char*)d_in[2];
  const float* Wc1  = (const float*)d_in[3];
  const float* bc1  = (const float*)d_in[4];
  const float* Wc2  = (const float*)d_in[5];
  const float* bc2  = (const float*)d_in[6];
  const float* Wd1  = (const float*)d_in[7];
  const float* bd1  = (const float*)d_in[8];
  const float* Wd2  = (const float*)d_in[9];
  const float* bd2  = (const float*)d_in[10];

  int N = in_sizes[0] / D_IN;
  int E = in_sizes[1] / 2;
  const int* src = ei;
  const int* dst = ei + E;
  float* out = (float*)d_out;

  char* w = (char*)d_ws; size_t off = 0;
  auto A = [&](size_t bytes)->void*{
    void* p = w + off;
    off += (bytes + 255) & ~(size_t)255;
    return p;
  };
  int*   deg    = (int*)  A((size_t)N*4);
  int*   rs     = (int*)  A((size_t)N*4);
  int*   bsums  = (int*)  A(256*4);
  float* dinv   = (float*)A((size_t)N*4);
  float* Mmat   = (float*)A((size_t)D_H*D_OUT*4);
  float* bvec   = (float*)A((size_t)D_OUT*4);
  int*   col    = (int*)  A((size_t)E*4);
  unsigned short* hq1 = (unsigned short*)A((size_t)N*64*2);   // 4 quarters x N*16 bf16 = 12.8 MB
  float* h      = (float*)A((size_t)N*D_H*4);                 // 25.6 MB
  unsigned short* hq2 = hq1;       // 4 x N*12 bf16 = 9.6 MB <= 12.8, hq1 dead after agg1
  int*   pos    = (int*)hq1;       // pos (6.4 MB) dead before gemm1 writes hq1
  float* tmp    = h;               // 16 MB <= 25.6, h dead after gemm2

  int Q1 = N*16;                   // shorts per quarter (hq1)
  int Q2 = N*12;                   // shorts per quarter (hq2)

  int NB  = (N + 1023) / 1024;
  int EB4 = (E + 1023) / 1024;     // 4 edges per thread
  int nb4 = (N + 3) / 4;
  int GA  = ((nb4 + 1) / 2) * 8;   // quarter-sharded agg grid (b%8 -> XCD pair)

  hipMemsetAsync(deg, 0, (size_t)N*4, stream);
  hipLaunchKernelGGL(k_degpos, dim3(EB4), dim3(256), 0, stream, dst, deg, pos, E);
  hipLaunchKernelGGL(k_scan1, dim3(NB), dim3(1024), 0, stream, deg, rs, bsums, N);
  hipLaunchKernelGGL(k_scan2, dim3(1), dim3(128), 0, stream, bsums, NB);
  hipLaunchKernelGGL(k_scan3, dim3(NB), dim3(1024), 0, stream, deg, rs, bsums, dinv, N);
  hipLaunchKernelGGL(k_scatter, dim3(EB4), dim3(256), 0, stream, src, dst, pos, rs, col, E);
  hipLaunchKernelGGL(k_pre,   dim3(1), dim3(256), 0, stream, Wd1, bd1, Wc2, Mmat, bvec);
  hipLaunchKernelGGL(k_gemm1, dim3((N+31)/32), dim3(256), 0, stream, x, Wc1, dinv, hq1, N, Q1);
  hipLaunchKernelGGL(k_agg1,  dim3(GA), dim3(256), 0, stream, hq1, rs, deg, col, dinv, bc1, h, N, Q1);
  hipLaunchKernelGGL(k_gemm2, dim3((N+127)/128), dim3(128), 0, stream, h, mask, Mmat, bvec, Wc2, dinv, hq2, N, Q2);
  hipLaunchKernelGGL(k_agg2,  dim3(GA), dim3(256), 0, stream, hq2, rs, deg, col, dinv, bc2, tmp, N, Q2);
  hipLaunchKernelGGL(k_post,  dim3(nb4), dim3(256), 0, stream, tmp, mask, Wd2, bd2, out, N);
}

// Round 10
// 459.320 us; speedup vs baseline: 1.3942x; 1.3942x over previous
//
#include <hip/hip_runtime.h>

#define D_IN  128
#define D_H   64
#define D_OUT 40

// ---- bf16 helpers (bit ops; RTNE pack) ----
__device__ __forceinline__ float bf_lo(unsigned u){ return __uint_as_float(u << 16); }
__device__ __forceinline__ float bf_hi(unsigned u){ return __uint_as_float(u & 0xFFFF0000u); }
__device__ __forceinline__ unsigned bf_pack(float a, float b){
  unsigned ua = __float_as_uint(a), ub = __float_as_uint(b);
  unsigned lo = (ua + 0x7FFFu + ((ua >> 16) & 1u)) >> 16;
  unsigned hi = (ub + 0x7FFFu + ((ub >> 16) & 1u)) & 0xFFFF0000u;
  return hi | lo;
}

// ---------------- CSR build: deg+pos in one atomic pass, then pure scatter ------

__launch_bounds__(256)
static __global__ void k_degpos(const int* __restrict__ dst, int* __restrict__ deg,
                                int* __restrict__ pos, int E){
  int base = (blockIdx.x*256 + threadIdx.x) * 4;
  if (base + 4 <= E){
    int4 d = *(const int4*)(dst + base);
    int4 p;
    p.x = atomicAdd(&deg[d.x], 1);
    p.y = atomicAdd(&deg[d.y], 1);
    p.z = atomicAdd(&deg[d.z], 1);
    p.w = atomicAdd(&deg[d.w], 1);
    *(int4*)(pos + base) = p;
  } else {
    for (int i = base; i < E; i++) pos[i] = atomicAdd(&deg[dst[i]], 1);
  }
}

static __global__ void k_scan1(const int* __restrict__ deg, int* __restrict__ incl,
                               int* __restrict__ bsums, int n){
  __shared__ int s[1024];
  int t = threadIdx.x; int g = blockIdx.x*1024 + t;
  int v = (g < n) ? deg[g] : 0;
  s[t] = v; __syncthreads();
  for (int off = 1; off < 1024; off <<= 1){
    int u = (t >= off) ? s[t-off] : 0; __syncthreads();
    s[t] += u; __syncthreads();
  }
  if (g < n) incl[g] = s[t];
  if (t == 1023) bsums[blockIdx.x] = s[1023];
}

static __global__ void k_scan2(int* bsums, int nb){
  __shared__ int s[128];
  int t = threadIdx.x;
  int v = (t < nb) ? bsums[t] : 0;
  s[t] = v; __syncthreads();
  for (int off = 1; off < 128; off <<= 1){
    int u = (t >= off) ? s[t-off] : 0; __syncthreads();
    s[t] += u; __syncthreads();
  }
  if (t < nb) bsums[t] = s[t] - v;   // exclusive block offsets
}

static __global__ void k_scan3(const int* __restrict__ deg, int* __restrict__ rs,
                               const int* __restrict__ bsums,
                               float* __restrict__ dinv, int n){
  int t = threadIdx.x; int g = blockIdx.x*1024 + t;
  if (g < n){
    int excl = rs[g] - deg[g] + bsums[blockIdx.x];
    rs[g] = excl;
    dinv[g] = rsqrtf((float)(deg[g] + 1));   // +1 = self loop
  }
}

__launch_bounds__(256)
static __global__ void k_scatter(const int* __restrict__ src, const int* __restrict__ dst,
                                 const int* __restrict__ pos, const int* __restrict__ rs,
                                 int* __restrict__ col, int E){
  int base = (blockIdx.x*256 + threadIdx.x) * 4;
  if (base + 4 <= E){
    int4 d = *(const int4*)(dst + base);
    int4 s = *(const int4*)(src + base);
    int4 p = *(const int4*)(pos + base);
    col[rs[d.x] + p.x] = s.x;
    col[rs[d.y] + p.y] = s.y;
    col[rs[d.z] + p.z] = s.z;
    col[rs[d.w] + p.w] = s.w;
  } else {
    for (int i = base; i < E; i++) col[rs[dst[i]] + pos[i]] = src[i];
  }
}

// ---------------- fold delete-MLP into GEMM2: M = Wd1^T @ Wc2, bvec = bd1 @ Wc2 -----

static __global__ void k_pre(const float* __restrict__ Wd1, const float* __restrict__ bd1,
                             const float* __restrict__ Wc2, float* __restrict__ M,
                             float* __restrict__ bvec){
  int t = threadIdx.x;
  for (int i = t; i < D_H*D_OUT; i += 256){
    int q = i / D_OUT, j = i % D_OUT;
    float s = 0.f;
    for (int k = 0; k < D_H; k++) s += Wd1[k*D_H + q] * Wc2[k*D_OUT + j];
    M[i] = s;
  }
  if (t < D_OUT){
    float s = 0.f;
    for (int k = 0; k < D_H; k++) s += bd1[k] * Wc2[k*D_OUT + t];
    bvec[t] = s;
  }
}

// ---------------- GEMM1: hws1b[n] = bf16( dinv[n] * (x[n] @ Wc1) ) ----------------

__launch_bounds__(256)
static __global__ void k_gemm1(const float* __restrict__ x, const float* __restrict__ Wc1,
                               const float* __restrict__ dinv,
                               unsigned short* __restrict__ hws1b, int n){
  __shared__ float Wl[D_IN*D_H];        // 32 KB
  __shared__ float xs[32][D_IN+1];      // padded
  int t = threadIdx.x;
  int base = blockIdx.x*32;
  for (int i = t; i < D_IN*D_H; i += 256) Wl[i] = Wc1[i];
  for (int i = t; i < 32*D_IN; i += 256){
    int r = i >> 7, c = i & 127;
    int node = base + r;
    xs[r][c] = (node < n) ? x[(size_t)node*D_IN + c] : 0.f;
  }
  __syncthreads();
  int nl = t >> 3, j0 = (t & 7)*8;
  int node = base + nl;
  if (node >= n) return;
  float acc[8] = {0,0,0,0,0,0,0,0};
  #pragma unroll 4
  for (int k = 0; k < D_IN; k++){
    float xv = xs[nl][k];
    #pragma unroll
    for (int jj = 0; jj < 8; jj++) acc[jj] += xv * Wl[k*D_H + j0 + jj];
  }
  float dv = dinv[node];
  uint4 o;
  o.x = bf_pack(acc[0]*dv, acc[1]*dv);
  o.y = bf_pack(acc[2]*dv, acc[3]*dv);
  o.z = bf_pack(acc[4]*dv, acc[5]*dv);
  o.w = bf_pack(acc[6]*dv, acc[7]*dv);
  *(uint4*)(hws1b + (size_t)node*D_H + j0) = o;
}

// ---------------- agg1: h = relu(dinv * (self + sum_in) + bc1) ----------------
// Branchless batched gathers: per step, 2 clamped col loads + 2 gathers issued
// unconditionally (cndmask zeroing after) -> 4 chains in flight with unroll 2.

__launch_bounds__(256)
static __global__ void k_agg1(const unsigned short* __restrict__ hws1b, const int* __restrict__ rs,
                              const int* __restrict__ deg, const int* __restrict__ col,
                              const float* __restrict__ dinv, const float* __restrict__ bc1,
                              float* __restrict__ h, int n){
  int t = threadIdx.x;
  int wave = t >> 6, lane = t & 63;
  int node = blockIdx.x*4 + wave;
  if (node >= n) return;
  int grp = lane >> 4, fl = lane & 15;
  const uint2* g2 = (const uint2*)hws1b;           // row = 16 uint2 (128B)
  float a0=0.f, a1=0.f, a2=0.f, a3=0.f;
  if (grp == 0){
    uint2 v = g2[(size_t)node*16 + fl];            // self loop
    a0 += bf_lo(v.x); a1 += bf_hi(v.x); a2 += bf_lo(v.y); a3 += bf_hi(v.y);
  }
  int s0 = rs[node], cnt = deg[node];
  int last = cnt - 1;
  #pragma unroll 2
  for (int e0 = 0; e0 < cnt; e0 += 8){
    int slA = e0 + grp, slB = e0 + 4 + grp;
    int sA = col[s0 + (slA <= last ? slA : last)];
    int sB = col[s0 + (slB <= last ? slB : last)];
    uint2 vA = g2[(size_t)sA*16 + fl];
    uint2 vB = g2[(size_t)sB*16 + fl];
    if (slA > last){ vA.x = 0u; vA.y = 0u; }
    if (slB > last){ vB.x = 0u; vB.y = 0u; }
    a0 += bf_lo(vA.x) + bf_lo(vB.x);
    a1 += bf_hi(vA.x) + bf_hi(vB.x);
    a2 += bf_lo(vA.y) + bf_lo(vB.y);
    a3 += bf_hi(vA.y) + bf_hi(vB.y);
  }
  a0 += __shfl_xor(a0, 16, 64); a1 += __shfl_xor(a1, 16, 64);
  a2 += __shfl_xor(a2, 16, 64); a3 += __shfl_xor(a3, 16, 64);
  a0 += __shfl_xor(a0, 32, 64); a1 += __shfl_xor(a1, 32, 64);
  a2 += __shfl_xor(a2, 32, 64); a3 += __shfl_xor(a3, 32, 64);
  if (grp == 0){
    float dv = dinv[node];
    float4 b = ((const float4*)bc1)[fl];
    float4 o;
    o.x = fmaxf(a0*dv + b.x, 0.f);
    o.y = fmaxf(a1*dv + b.y, 0.f);
    o.z = fmaxf(a2*dv + b.z, 0.f);
    o.w = fmaxf(a3*dv + b.w, 0.f);
    ((float4*)h)[(size_t)node*16 + fl] = o;
  }
}

// ---------------- GEMM2 (+ folded delete MLP): hws2b[n] = bf16(dinv * (h @ (mask?M:Wc2))) --

__launch_bounds__(128)
static __global__ void k_gemm2(const float* __restrict__ h, const unsigned char* __restrict__ mask,
                               const float* __restrict__ Mmat, const float* __restrict__ bvec,
                               const float* __restrict__ Wc2, const float* __restrict__ dinv,
                               unsigned short* __restrict__ hws2b, int n){
  __shared__ float Ms[D_H*D_OUT];          // 10 KB
  __shared__ float Ws[D_H*D_OUT];          // 10 KB
  __shared__ float bv[D_OUT];
  __shared__ float hs[128*(D_H+1)];        // 33.3 KB, padded stride 65
  int t = threadIdx.x;
  int base = blockIdx.x*128;
  for (int i = t; i < D_H*D_OUT; i += 128){ Ms[i] = Mmat[i]; Ws[i] = Wc2[i]; }
  if (t < D_OUT) bv[t] = bvec[t];
  for (int i = t; i < 128*D_H; i += 128){
    int r = i >> 6, c = i & 63;
    int node = base + r;
    hs[r*(D_H+1) + c] = (node < n) ? h[(size_t)node*D_H + c] : 0.f;
  }
  __syncthreads();
  int node = base + t;
  if (node >= n) return;
  bool m = mask[node] != 0;
  const float* Wp = m ? Ms : Ws;
  float acc[D_OUT];
  #pragma unroll
  for (int j = 0; j < D_OUT; j++) acc[j] = m ? bv[j] : 0.f;
  const float* hrow = &hs[t*(D_H+1)];
  for (int q = 0; q < D_H; q++){
    float hv = hrow[q];
    #pragma unroll
    for (int j = 0; j < D_OUT; j++) acc[j] += hv * Wp[q*D_OUT + j];
  }
  float dv = dinv[node];
  unsigned short* op = hws2b + (size_t)node*D_OUT;
  #pragma unroll
  for (int k = 0; k < 5; k++){
    uint4 o;
    o.x = bf_pack(acc[k*8+0]*dv, acc[k*8+1]*dv);
    o.y = bf_pack(acc[k*8+2]*dv, acc[k*8+3]*dv);
    o.z = bf_pack(acc[k*8+4]*dv, acc[k*8+5]*dv);
    o.w = bf_pack(acc[k*8+6]*dv, acc[k*8+7]*dv);
    *(uint4*)(op + k*8) = o;
  }
}

// ---------------- agg2 + final delete epilogue -> out ----------------
// Branchless batched gathers (clamped fl for lanes >=10; their accs never mix
// into active lanes: xor-16/32 reduction preserves fl). Epilogue as in R8.

__launch_bounds__(256)
static __global__ void k_agg2(const unsigned short* __restrict__ hws2b, const int* __restrict__ rs,
                              const int* __restrict__ deg, const int* __restrict__ col,
                              const float* __restrict__ dinv, const float* __restrict__ bc2,
                              const unsigned char* __restrict__ mask,
                              const float* __restrict__ Wd2, const float* __restrict__ bd2,
                              float* __restrict__ out, int n){
  __shared__ float4 wds4[D_OUT*11];        // Wd2 row j at wds4[j*11+q], q=0..9
  __shared__ float  bds[D_OUT];
  __shared__ float4 os4[4][11];            // per-wave res row (10 float4 used)
  int t = threadIdx.x;
  for (int i = t; i < D_OUT*10; i += 256){
    int j = i / 10, q = i % 10;
    const float* wr = Wd2 + j*D_OUT + q*4;
    wds4[j*11 + q] = make_float4(wr[0], wr[1], wr[2], wr[3]);
  }
  if (t < D_OUT) bds[t] = bd2[t];
  __syncthreads();
  int wave = t >> 6, lane = t & 63;
  int node = blockIdx.x*4 + wave;
  if (node >= n) return;
  int grp = lane >> 4, fl = lane & 15;
  bool fa = fl < 10;                       // 10 uint2 = 40 bf16
  int flc = fa ? fl : 9;                   // clamped lane offset (legal address)
  const uint2* g2 = (const uint2*)hws2b;   // row = 10 uint2 (80B)
  float a0=0.f, a1=0.f, a2=0.f, a3=0.f;
  if (grp == 0 && fa){
    uint2 v = g2[(size_t)node*10 + fl];    // self loop
    a0 += bf_lo(v.x); a1 += bf_hi(v.x); a2 += bf_lo(v.y); a3 += bf_hi(v.y);
  }
  int s0 = rs[node], cnt = deg[node];
  int last = cnt - 1;
  #pragma unroll 2
  for (int e0 = 0; e0 < cnt; e0 += 8){
    int slA = e0 + grp, slB = e0 + 4 + grp;
    int sA = col[s0 + (slA <= last ? slA : last)];
    int sB = col[s0 + (slB <= last ? slB : last)];
    uint2 vA = g2[(size_t)sA*10 + flc];
    uint2 vB = g2[(size_t)sB*10 + flc];
    if (slA > last){ vA.x = 0u; vA.y = 0u; }
    if (slB > last){ vB.x = 0u; vB.y = 0u; }
    a0 += bf_lo(vA.x) + bf_lo(vB.x);
    a1 += bf_hi(vA.x) + bf_hi(vB.x);
    a2 += bf_lo(vA.y) + bf_lo(vB.y);
    a3 += bf_hi(vA.y) + bf_hi(vB.y);
  }
  a0 += __shfl_xor(a0, 16, 64); a1 += __shfl_xor(a1, 16, 64);
  a2 += __shfl_xor(a2, 16, 64); a3 += __shfl_xor(a3, 16, 64);
  a0 += __shfl_xor(a0, 32, 64); a1 += __shfl_xor(a1, 32, 64);
  a2 += __shfl_xor(a2, 32, 64); a3 += __shfl_xor(a3, 32, 64);
  // all active lanes now hold reduced sums for elements 4fl..4fl+3
  float dv = dinv[node];
  float4 res = make_float4(0.f, 0.f, 0.f, 0.f);
  if (fa){
    float4 b = ((const float4*)bc2)[fl];
    res.x = a0*dv + b.x;
    res.y = a1*dv + b.y;
    res.z = a2*dv + b.z;
    res.w = a3*dv + b.w;
  }
  if (mask[node] != 0){                    // wave-uniform branch
    if (grp == 0 && fa) os4[wave][fl] = res;      // stage res row (1 ds_write_b128)
    int J = grp*10 + fl;                          // 40 lanes own one output row each
    float r = 0.f;
    if (fa) r = bds[J];
    #pragma unroll
    for (int q = 0; q < 10; q++){
      float4 hv = os4[wave][q];                   // broadcast read (same addr)
      if (fa){
        float4 wv = wds4[J*11 + q];
        r += hv.x*wv.x + hv.y*wv.y + hv.z*wv.z + hv.w*wv.w;
      }
    }
    if (fa) out[(size_t)node*D_OUT + J] = r;
  } else if (grp == 0 && fa){
    ((float4*)out)[(size_t)node*10 + fl] = res;
  }
}

// ---------------- launcher ----------------

extern "C" void kernel_launch(void* const* d_in, const int* in_sizes, int n_in,
                              void* d_out, int out_size, void* d_ws, size_t ws_size,
                              hipStream_t stream){
  const float* x    = (const float*)d_in[0];
  const int*   ei   = (const int*)d_in[1];
  const unsigned char* mask = (const unsigned char*)d_in[2];
  const float* Wc1  = (const float*)d_in[3];
  const float* bc1  = (const float*)d_in[4];
  const float* Wc2  = (const float*)d_in[5];
  const float* bc2  = (const float*)d_in[6];
  const float* Wd1  = (const float*)d_in[7];
  const float* bd1  = (const float*)d_in[8];
  const float* Wd2  = (const float*)d_in[9];
  const float* bd2  = (const float*)d_in[10];

  int N = in_sizes[0] / D_IN;
  int E = in_sizes[1] / 2;
  const int* src = ei;
  const int* dst = ei + E;
  float* out = (float*)d_out;

  char* w = (char*)d_ws; size_t off = 0;
  auto A = [&](size_t bytes)->void*{
    void* p = w + off;
    off += (bytes + 255) & ~(size_t)255;
    return p;
  };
  int*   deg    = (int*)  A((size_t)N*4);
  int*   rs     = (int*)  A((size_t)N*4);
  int*   bsums  = (int*)  A(256*4);
  float* dinv   = (float*)A((size_t)N*4);
  float* Mmat   = (float*)A((size_t)D_H*D_OUT*4);
  float* bvec   = (float*)A((size_t)D_OUT*4);
  int*   col    = (int*)  A((size_t)E*4);
  unsigned short* hws1b = (unsigned short*)A((size_t)N*D_H*2);   // 12.8 MB
  float* h      = (float*)A((size_t)N*D_H*4);
  unsigned short* hws2b = hws1b;   // hws1b dead after agg1 -> reuse
  int*   pos    = (int*)hws1b;     // pos dead before gemm1 writes hws1b

  int NB  = (N + 1023) / 1024;
  int EB4 = (E + 1023) / 1024;   // 4 edges per thread

  hipMemsetAsync(deg, 0, (size_t)N*4, stream);
  hipLaunchKernelGGL(k_degpos, dim3(EB4), dim3(256), 0, stream, dst, deg, pos, E);
  hipLaunchKernelGGL(k_scan1, dim3(NB), dim3(1024), 0, stream, deg, rs, bsums, N);
  hipLaunchKernelGGL(k_scan2, dim3(1), dim3(128), 0, stream, bsums, NB);
  hipLaunchKernelGGL(k_scan3, dim3(NB), dim3(1024), 0, stream, deg, rs, bsums, dinv, N);
  hipLaunchKernelGGL(k_scatter, dim3(EB4), dim3(256), 0, stream, src, dst, pos, rs, col, E);
  hipLaunchKernelGGL(k_pre,   dim3(1), dim3(256), 0, stream, Wd1, bd1, Wc2, Mmat, bvec);
  hipLaunchKernelGGL(k_gemm1, dim3((N+31)/32), dim3(256), 0, stream, x, Wc1, dinv, hws1b, N);
  hipLaunchKernelGGL(k_agg1,  dim3((N+3)/4), dim3(256), 0, stream, hws1b, rs, deg, col, dinv, bc1, h, N);
  hipLaunchKernelGGL(k_gemm2, dim3((N+127)/128), dim3(128), 0, stream, h, mask, Mmat, bvec, Wc2, dinv, hws2b, N);
  hipLaunchKernelGGL(k_agg2,  dim3((N+3)/4), dim3(256), 0, stream, hws2b, rs, deg, col, dinv, bc2, mask, Wd2, bd2, out, N);
}